// Round 1
// baseline (111.570 us; speedup 1.0000x reference)
//
#include <hip/hip_runtime.h>

// GPUTimeMask: x (B=64, C=16, T=60000) fp32; starts/widths (NUM_MASKS=2, B) int32.
// Zero x[b, :, t] for t in [start, start+clip(width,1,150)) for each of 2 masks.
// Memory-bound streaming op: float4 in, float4 out, grid-stride.

#define B_DIM 64
#define C_DIM 16
#define T_DIM 60000
#define MAXW 150

// float4 units: per row T/4 = 15000, per batch C*T/4 = 240000, total = 15,360,000
#define T4 (T_DIM / 4)
#define BATCH4 (C_DIM * T4)
#define TOTAL4 (B_DIM * BATCH4)

__global__ __launch_bounds__(256) void GPUTimeMask_38010460570421_kernel(
    const float4* __restrict__ x,
    const int* __restrict__ starts,   // (2, B) row-major
    const int* __restrict__ widths,   // (2, B) row-major
    float4* __restrict__ out) {
    int idx = blockIdx.x * blockDim.x + threadIdx.x;
    int stride = gridDim.x * blockDim.x;
    for (int i = idx; i < TOTAL4; i += stride) {
        int b = i / BATCH4;
        int t = (i % T4) * 4;   // valid: BATCH4 is a multiple of T4

        int s0 = starts[b];
        int s1 = starts[B_DIM + b];
        int w0 = widths[b];
        int w1 = widths[B_DIM + b];
        w0 = min(max(w0, 1), MAXW);
        w1 = min(max(w1, 1), MAXW);
        int e0 = s0 + w0;
        int e1 = s1 + w1;

        float4 v = x[i];
        float pv[4] = {v.x, v.y, v.z, v.w};
        #pragma unroll
        for (int j = 0; j < 4; ++j) {
            int tj = t + j;
            bool m = (tj >= s0 && tj < e0) || (tj >= s1 && tj < e1);
            pv[j] = m ? 0.0f : pv[j];
        }
        v.x = pv[0]; v.y = pv[1]; v.z = pv[2]; v.w = pv[3];
        out[i] = v;
    }
}

extern "C" void kernel_launch(void* const* d_in, const int* in_sizes, int n_in,
                              void* d_out, int out_size, void* d_ws, size_t ws_size,
                              hipStream_t stream) {
    const float4* x = (const float4*)d_in[0];
    const int* starts = (const int*)d_in[1];
    const int* widths = (const int*)d_in[2];
    float4* out = (float4*)d_out;

    const int threads = 256;
    const int blocks = 2048;  // ~8 blocks/CU; grid-stride covers TOTAL4
    hipLaunchKernelGGL(GPUTimeMask_38010460570421_kernel,
                       dim3(blocks), dim3(threads), 0, stream,
                       x, starts, widths, out);
}

// Round 2
// 100.781 us; speedup vs baseline: 1.1071x; 1.1071x over previous
//
#include <hip/hip_runtime.h>

// GPUTimeMask: x (B=64, C=16, T=60000) fp32; starts/widths (NUM_MASKS=2, B) int32.
// Zero x[b, :, t] for t in [start, start+clip(width,1,150)) for each of 2 masks.
//
// Strategy: masked region is <=0.5% of elements. Do a full-speed D2D copy
// (hipMemcpyAsync -> AMD's tuned copy path, ~85% of HBM peak), then a tiny
// fixup kernel that zero-stores only the masked spans (2*64 blocks, <=2400
// floats each).

#define B_DIM 64
#define C_DIM 16
#define T_DIM 60000
#define MAXW 150
#define NUM_MASKS 2

__global__ __launch_bounds__(256) void GPUTimeMask_38010460570421_fixup(
    const int* __restrict__ starts,   // (2, B) flat
    const int* __restrict__ widths,   // (2, B) flat
    float* __restrict__ out) {
    int mb = blockIdx.x;              // 0 .. NUM_MASKS*B_DIM-1, = m*B_DIM + b
    int b  = mb & (B_DIM - 1);

    int s = starts[mb];
    int w = widths[mb];
    w = min(max(w, 1), MAXW);

    int tid = threadIdx.x;
    if (tid < w) {
        long base = (long)b * C_DIM * T_DIM + s + tid;
        #pragma unroll
        for (int c = 0; c < C_DIM; ++c) {
            out[base + (long)c * T_DIM] = 0.0f;
        }
    }
}

extern "C" void kernel_launch(void* const* d_in, const int* in_sizes, int n_in,
                              void* d_out, int out_size, void* d_ws, size_t ws_size,
                              hipStream_t stream) {
    const float* x = (const float*)d_in[0];
    const int* starts = (const int*)d_in[1];
    const int* widths = (const int*)d_in[2];
    float* out = (float*)d_out;

    size_t nbytes = (size_t)B_DIM * C_DIM * T_DIM * sizeof(float);
    hipMemcpyAsync(out, x, nbytes, hipMemcpyDeviceToDevice, stream);

    hipLaunchKernelGGL(GPUTimeMask_38010460570421_fixup,
                       dim3(NUM_MASKS * B_DIM), dim3(256), 0, stream,
                       starts, widths, out);
}